// Round 2
// baseline (850.921 us; speedup 1.0000x reference)
//
#include <hip/hip_runtime.h>
#include <hip/hip_bf16.h>

#define D 64

// ---------------------------------------------------------------------------
// K1: out-degree histogram over source nodes (int atomics)
__global__ __launch_bounds__(256) void deg_kernel(const int* __restrict__ n1,
                                                  int* __restrict__ cnt, int E) {
    int e = blockIdx.x * 256 + threadIdx.x;
    if (e < E) atomicAdd(&cnt[n1[e]], 1);
}

// K2: single-block exclusive scan over cnt[N] -> row_ptr/cursor, plus
//     rd[i] = rsqrt(deg[i]).  1024 threads, each owns a contiguous chunk.
__global__ __launch_bounds__(1024) void scan_kernel(const int* __restrict__ cnt,
                                                    int* __restrict__ row_ptr,
                                                    int* __restrict__ cursor,
                                                    float* __restrict__ rd,
                                                    int N, int E) {
    int t = threadIdx.x;
    int C = (N + 1023) / 1024;           // chunk size (98 for N=100000)
    int s = t * C;
    int e = min(s + C, N);
    int sum = 0;
    for (int i = s; i < e; ++i) sum += cnt[i];

    __shared__ int lds[1024];
    lds[t] = sum;
    __syncthreads();
    #pragma unroll
    for (int off = 1; off < 1024; off <<= 1) {
        int v = (t >= off) ? lds[t - off] : 0;
        __syncthreads();
        lds[t] += v;
        __syncthreads();
    }
    int run = lds[t] - sum;              // exclusive prefix of this chunk
    for (int i = s; i < e; ++i) {
        int c = cnt[i];
        row_ptr[i] = run;
        cursor[i]  = run;
        rd[i]      = rsqrtf((float)c);   // deg >= 1 guaranteed (every node a source)
        run += c;
    }
    if (t == 0) row_ptr[N] = E;
}

// K3: h = X @ W^T + b.  One wave per row; lane d owns output dim d.
__global__ __launch_bounds__(256) void linear_kernel(const float* __restrict__ x,
                                                     const float* __restrict__ W,
                                                     const float* __restrict__ b,
                                                     float* __restrict__ h, int N) {
    __shared__ float Wt[D][D];
    __shared__ float bs[D];
    int tid = threadIdx.x;
    for (int i = tid; i < D * D; i += 256) {
        int d = i >> 6, k = i & 63;
        Wt[k][d] = W[i];
    }
    if (tid < D) bs[tid] = b[tid];
    __syncthreads();

    int lane = tid & 63;
    int wave = tid >> 6;
    for (int row = blockIdx.x * 4 + wave; row < N; row += gridDim.x * 4) {
        float xl  = x[row * D + lane];
        float acc = bs[lane];
        #pragma unroll
        for (int k = 0; k < D; ++k) {
            float xv = __shfl(xl, k, 64);
            acc += xv * Wt[k][lane];
        }
        h[row * D + lane] = acc;
    }
}

// K4: CSR fill. Edge e -> slot in its source node's segment; store packed
//     {n2, wd = rd[n2]*exp(-d^2)} so the agg kernel reads one 8B record/edge.
__global__ __launch_bounds__(256) void fill_kernel(const int* __restrict__ ei,
                                                   const float* __restrict__ dist,
                                                   const float* __restrict__ rd,
                                                   int* __restrict__ cursor,
                                                   uint2* __restrict__ csr, int E) {
    int e = blockIdx.x * 256 + threadIdx.x;
    if (e >= E) return;
    int   n1 = ei[e];
    int   n2 = ei[E + e];
    float dv = dist[e];
    float wd = rd[n2] * __expf(-dv * dv);
    int slot = atomicAdd(&cursor[n1], 1);
    csr[slot] = make_uint2((unsigned)n2, __float_as_uint(wd));
}

// K5: gather-side aggregation + leaky_relu + L2-normalize, fused.
//     One wave per node; lane d owns dim d; register accumulate, single write.
__global__ __launch_bounds__(256) void agg_kernel(const int* __restrict__ row_ptr,
                                                  const float* __restrict__ rd,
                                                  const uint2* __restrict__ csr,
                                                  const float* __restrict__ h,
                                                  float* __restrict__ out, int N) {
    int node = blockIdx.x * 4 + (threadIdx.x >> 6);
    int lane = threadIdx.x & 63;
    if (node >= N) return;
    int s = row_ptr[node];
    int e = row_ptr[node + 1];
    float acc = 0.0f;
    for (int j = s; j < e; ++j) {
        uint2 p  = csr[j];                       // wave-broadcast 8B
        float wd = __uint_as_float(p.y);
        acc += wd * h[(size_t)p.x * D + lane];   // 256B coalesced gather
    }
    acc *= rd[node];                             // the rd[n1] factor, hoisted
    float v = acc > 0.0f ? acc : 0.01f * acc;
    float ss = v * v;
    #pragma unroll
    for (int m = 32; m; m >>= 1) ss += __shfl_xor(ss, m, 64);
    out[node * D + lane] = v / fmaxf(sqrtf(ss), 1e-12f);
}

extern "C" void kernel_launch(void* const* d_in, const int* in_sizes, int n_in,
                              void* d_out, int out_size, void* d_ws, size_t ws_size,
                              hipStream_t stream) {
    const float* poi  = (const float*)d_in[0];
    const int*   ei   = (const int*)d_in[1];
    const float* dist = (const float*)d_in[2];
    const float* W    = (const float*)d_in[3];
    const float* b    = (const float*)d_in[4];
    float*       out  = (float*)d_out;

    int N = in_sizes[0] / D;   // 100000
    int E = in_sizes[2];       // 1280000

    // workspace layout (all offsets 512KB-aligned where it matters):
    char*  w       = (char*)d_ws;
    int*   cnt     = (int*)(w);                         // N ints
    int*   row_ptr = (int*)(w + 0x80000);               // N+1 ints
    int*   cursor  = (int*)(w + 0x100000);              // N ints
    float* rd      = (float*)(w + 0x180000);            // N floats
    float* h       = (float*)(w + 0x200000);            // N*D floats (25.6MB)
    uint2* csr     = (uint2*)(w + 0x200000 + (size_t)N * D * sizeof(float)); // E*8B

    hipMemsetAsync(cnt, 0, (size_t)N * sizeof(int), stream);

    deg_kernel   <<<(E + 255) / 256, 256, 0, stream>>>(ei, cnt, E);
    scan_kernel  <<<1, 1024, 0, stream>>>(cnt, row_ptr, cursor, rd, N, E);
    linear_kernel<<<(N + 3) / 4, 256, 0, stream>>>(poi, W, b, h, N);
    fill_kernel  <<<(E + 255) / 256, 256, 0, stream>>>(ei, dist, rd, cursor, csr, E);
    agg_kernel   <<<(N + 3) / 4, 256, 0, stream>>>(row_ptr, rd, csr, h, out, N);
}

// Round 3
// 601.612 us; speedup vs baseline: 1.4144x; 1.4144x over previous
//
#include <hip/hip_runtime.h>
#include <hip/hip_bf16.h>

#define D 64

// ---------------------------------------------------------------------------
// K1: out-degree histogram over source nodes (int atomics)
__global__ __launch_bounds__(256) void deg_kernel(const int* __restrict__ n1,
                                                  int* __restrict__ cnt, int E) {
    int e = blockIdx.x * 256 + threadIdx.x;
    if (e < E) atomicAdd(&cnt[n1[e]], 1);
}

// ---------------------------------------------------------------------------
// 3-phase parallel exclusive scan over cnt[N]  (1024 elems per block)
// Phase A: per-block sums
__global__ __launch_bounds__(256) void scanA_kernel(const int* __restrict__ cnt,
                                                    int* __restrict__ bsum, int N) {
    int t = threadIdx.x;
    int base = blockIdx.x * 1024 + t * 4;
    int s = 0;
    if (base + 3 < N) {
        int4 v = *(const int4*)(cnt + base);
        s = v.x + v.y + v.z + v.w;
    } else {
        for (int i = base; i < N && i < base + 4; ++i) s += cnt[i];
    }
    #pragma unroll
    for (int m = 32; m; m >>= 1) s += __shfl_xor(s, m, 64);
    __shared__ int ws[4];
    if ((t & 63) == 0) ws[t >> 6] = s;
    __syncthreads();
    if (t == 0) bsum[blockIdx.x] = ws[0] + ws[1] + ws[2] + ws[3];
}

// Phase B: exclusive scan of block sums (nb <= 128), single tiny block
__global__ __launch_bounds__(128) void scanB_kernel(int* __restrict__ bsum, int nb) {
    __shared__ int lds[128];
    int t = threadIdx.x;
    int v = (t < nb) ? bsum[t] : 0;
    lds[t] = v;
    __syncthreads();
    #pragma unroll
    for (int off = 1; off < 128; off <<= 1) {
        int u = (t >= off) ? lds[t - off] : 0;
        __syncthreads();
        lds[t] += u;
        __syncthreads();
    }
    if (t < nb) bsum[t] = lds[t] - v;   // exclusive
}

// Phase C: per-block local prefix + global offset; emit row_ptr, cursor, rd
__global__ __launch_bounds__(256) void scanC_kernel(const int* __restrict__ cnt,
                                                    const int* __restrict__ bsum,
                                                    int* __restrict__ row_ptr,
                                                    int* __restrict__ cursor,
                                                    float* __restrict__ rd,
                                                    int N, int E) {
    int t = threadIdx.x;
    int base = blockIdx.x * 1024 + t * 4;
    int c0 = 0, c1 = 0, c2 = 0, c3 = 0;
    if (base + 3 < N) {
        int4 v = *(const int4*)(cnt + base);
        c0 = v.x; c1 = v.y; c2 = v.z; c3 = v.w;
    } else {
        if (base + 0 < N) c0 = cnt[base + 0];
        if (base + 1 < N) c1 = cnt[base + 1];
        if (base + 2 < N) c2 = cnt[base + 2];
        if (base + 3 < N) c3 = cnt[base + 3];
    }
    int s = c0 + c1 + c2 + c3;
    __shared__ int lds[256];
    lds[t] = s;
    __syncthreads();
    #pragma unroll
    for (int off = 1; off < 256; off <<= 1) {
        int u = (t >= off) ? lds[t - off] : 0;
        __syncthreads();
        lds[t] += u;
        __syncthreads();
    }
    int run = bsum[blockIdx.x] + lds[t] - s;   // exclusive prefix of element base
    int cc[4] = {c0, c1, c2, c3};
    #pragma unroll
    for (int k = 0; k < 4; ++k) {
        int i = base + k;
        if (i < N) {
            row_ptr[i] = run;
            cursor[i]  = run;
            rd[i]      = rsqrtf((float)cc[k]);  // deg >= 1 guaranteed
            run += cc[k];
        }
    }
    if (blockIdx.x == 0 && t == 0) row_ptr[N] = E;
}

// ---------------------------------------------------------------------------
// K3: h = X @ W^T + b.  One wave per row; lane d owns output dim d.
__global__ __launch_bounds__(256) void linear_kernel(const float* __restrict__ x,
                                                     const float* __restrict__ W,
                                                     const float* __restrict__ b,
                                                     float* __restrict__ h, int N) {
    __shared__ float Wt[D][D];
    __shared__ float bs[D];
    int tid = threadIdx.x;
    for (int i = tid; i < D * D; i += 256) {
        int d = i >> 6, k = i & 63;
        Wt[k][d] = W[i];
    }
    if (tid < D) bs[tid] = b[tid];
    __syncthreads();

    int lane = tid & 63;
    int wave = tid >> 6;
    for (int row = blockIdx.x * 4 + wave; row < N; row += gridDim.x * 4) {
        float xl  = x[row * D + lane];
        float acc = bs[lane];
        #pragma unroll
        for (int k = 0; k < D; ++k) {
            float xv = __shfl(xl, k, 64);
            acc += xv * Wt[k][lane];
        }
        h[row * D + lane] = acc;
    }
}

// K4: CSR fill. Edge e -> slot in its source node's segment; store packed
//     {n2, wd = rd[n2]*exp(-d^2)}.
__global__ __launch_bounds__(256) void fill_kernel(const int* __restrict__ ei,
                                                   const float* __restrict__ dist,
                                                   const float* __restrict__ rd,
                                                   int* __restrict__ cursor,
                                                   uint2* __restrict__ csr, int E) {
    int e = blockIdx.x * 256 + threadIdx.x;
    if (e >= E) return;
    int   n1 = ei[e];
    int   n2 = ei[E + e];
    float dv = dist[e];
    float wd = rd[n2] * __expf(-dv * dv);
    int slot = atomicAdd(&cursor[n1], 1);
    csr[slot] = make_uint2((unsigned)n2, __float_as_uint(wd));
}

// K5: gather-side aggregation + leaky_relu + L2-normalize, fused.
__global__ __launch_bounds__(256) void agg_kernel(const int* __restrict__ row_ptr,
                                                  const float* __restrict__ rd,
                                                  const uint2* __restrict__ csr,
                                                  const float* __restrict__ h,
                                                  float* __restrict__ out, int N) {
    int node = blockIdx.x * 4 + (threadIdx.x >> 6);
    int lane = threadIdx.x & 63;
    if (node >= N) return;
    int s = row_ptr[node];
    int e = row_ptr[node + 1];
    float acc = 0.0f;
    for (int j = s; j < e; ++j) {
        uint2 p  = csr[j];
        float wd = __uint_as_float(p.y);
        acc += wd * h[(size_t)p.x * D + lane];
    }
    acc *= rd[node];
    float v = acc > 0.0f ? acc : 0.01f * acc;
    float ss = v * v;
    #pragma unroll
    for (int m = 32; m; m >>= 1) ss += __shfl_xor(ss, m, 64);
    out[node * D + lane] = v / fmaxf(sqrtf(ss), 1e-12f);
}

extern "C" void kernel_launch(void* const* d_in, const int* in_sizes, int n_in,
                              void* d_out, int out_size, void* d_ws, size_t ws_size,
                              hipStream_t stream) {
    const float* poi  = (const float*)d_in[0];
    const int*   ei   = (const int*)d_in[1];
    const float* dist = (const float*)d_in[2];
    const float* W    = (const float*)d_in[3];
    const float* b    = (const float*)d_in[4];
    float*       out  = (float*)d_out;

    int N = in_sizes[0] / D;   // 100000
    int E = in_sizes[2];       // 1280000

    char*  w       = (char*)d_ws;
    int*   cnt     = (int*)(w);                         // N ints
    int*   row_ptr = (int*)(w + 0x80000);               // N+1 ints
    int*   cursor  = (int*)(w + 0x100000);              // N ints
    float* rd      = (float*)(w + 0x180000);            // N floats
    int*   bsum    = (int*)(w + 0x1C0000);              // up to 128 ints
    float* h       = (float*)(w + 0x200000);            // N*D floats (25.6MB)
    uint2* csr     = (uint2*)(w + 0x200000 + (size_t)N * D * sizeof(float)); // E*8B

    int nb = (N + 1023) / 1024;   // 98 for N=100000 (must be <= 128)

    hipMemsetAsync(cnt, 0, (size_t)N * sizeof(int), stream);

    deg_kernel   <<<(E + 255) / 256, 256, 0, stream>>>(ei, cnt, E);
    scanA_kernel <<<nb, 256, 0, stream>>>(cnt, bsum, N);
    scanB_kernel <<<1, 128, 0, stream>>>(bsum, nb);
    scanC_kernel <<<nb, 256, 0, stream>>>(cnt, bsum, row_ptr, cursor, rd, N, E);
    linear_kernel<<<(N + 3) / 4, 256, 0, stream>>>(poi, W, b, h, N);
    fill_kernel  <<<(E + 255) / 256, 256, 0, stream>>>(ei, dist, rd, cursor, csr, E);
    agg_kernel   <<<(N + 3) / 4, 256, 0, stream>>>(row_ptr, rd, csr, h, out, N);
}

// Round 5
// 356.774 us; speedup vs baseline: 2.3850x; 1.6863x over previous
//
#include <hip/hip_runtime.h>
#include <hip/hip_bf16.h>

#define D 64

// ---------------------------------------------------------------------------
// K1: out-degree histogram over source nodes (int atomics)
__global__ __launch_bounds__(256) void deg_kernel(const int* __restrict__ n1,
                                                  int* __restrict__ cnt, int E) {
    int e = blockIdx.x * 256 + threadIdx.x;
    if (e < E) atomicAdd(&cnt[n1[e]], 1);
}

// ---------------------------------------------------------------------------
// 3-phase parallel exclusive scan over cnt[N]  (1024 elems per block)
__global__ __launch_bounds__(256) void scanA_kernel(const int* __restrict__ cnt,
                                                    int* __restrict__ bsum, int N) {
    int t = threadIdx.x;
    int base = blockIdx.x * 1024 + t * 4;
    int s = 0;
    if (base + 3 < N) {
        int4 v = *(const int4*)(cnt + base);
        s = v.x + v.y + v.z + v.w;
    } else {
        for (int i = base; i < N && i < base + 4; ++i) s += cnt[i];
    }
    #pragma unroll
    for (int m = 32; m; m >>= 1) s += __shfl_xor(s, m, 64);
    __shared__ int ws[4];
    if ((t & 63) == 0) ws[t >> 6] = s;
    __syncthreads();
    if (t == 0) bsum[blockIdx.x] = ws[0] + ws[1] + ws[2] + ws[3];
}

__global__ __launch_bounds__(128) void scanB_kernel(int* __restrict__ bsum, int nb) {
    __shared__ int lds[128];
    int t = threadIdx.x;
    int v = (t < nb) ? bsum[t] : 0;
    lds[t] = v;
    __syncthreads();
    #pragma unroll
    for (int off = 1; off < 128; off <<= 1) {
        int u = (t >= off) ? lds[t - off] : 0;
        __syncthreads();
        lds[t] += u;
        __syncthreads();
    }
    if (t < nb) bsum[t] = lds[t] - v;   // exclusive
}

__global__ __launch_bounds__(256) void scanC_kernel(const int* __restrict__ cnt,
                                                    const int* __restrict__ bsum,
                                                    int* __restrict__ row_ptr,
                                                    int* __restrict__ cursor,
                                                    float* __restrict__ rd,
                                                    int N, int E) {
    int t = threadIdx.x;
    int base = blockIdx.x * 1024 + t * 4;
    int c0 = 0, c1 = 0, c2 = 0, c3 = 0;
    if (base + 3 < N) {
        int4 v = *(const int4*)(cnt + base);
        c0 = v.x; c1 = v.y; c2 = v.z; c3 = v.w;
    } else {
        if (base + 0 < N) c0 = cnt[base + 0];
        if (base + 1 < N) c1 = cnt[base + 1];
        if (base + 2 < N) c2 = cnt[base + 2];
        if (base + 3 < N) c3 = cnt[base + 3];
    }
    int s = c0 + c1 + c2 + c3;
    __shared__ int lds[256];
    lds[t] = s;
    __syncthreads();
    #pragma unroll
    for (int off = 1; off < 256; off <<= 1) {
        int u = (t >= off) ? lds[t - off] : 0;
        __syncthreads();
        lds[t] += u;
        __syncthreads();
    }
    int run = bsum[blockIdx.x] + lds[t] - s;
    int cc[4] = {c0, c1, c2, c3};
    #pragma unroll
    for (int k = 0; k < 4; ++k) {
        int i = base + k;
        if (i < N) {
            row_ptr[i] = run;
            cursor[i]  = run;
            rd[i]      = rsqrtf((float)cc[k]);  // deg >= 1 guaranteed
            run += cc[k];
        }
    }
    if (blockIdx.x == 0 && t == 0) row_ptr[N] = E;
}

// ---------------------------------------------------------------------------
// K3: h = X @ W^T + b.  Register-blocked f32 GEMM.
// Block = 256 threads handles 64 rows. X tile staged TRANSPOSED in LDS
// (Xs[k][r], pad +4 keeps float4 alignment), W^T staged once (Ws[k][d]).
// Thread (tr,tc) computes a 4x4 output tile: per k, 2 ds_read_b128 -> 16 FMA.
__global__ __launch_bounds__(256) void linear_kernel(const float* __restrict__ x,
                                                     const float* __restrict__ W,
                                                     const float* __restrict__ b,
                                                     float* __restrict__ h, int N) {
    __shared__ float Ws[D][D + 4];   // Ws[k][d] = W[d*64+k]
    __shared__ float Xs[D][D + 4];   // Xs[k][r] = X[row0+r][k]
    __shared__ float bs[D];
    int t = threadIdx.x;

    // stage W^T (one-time): thread t loads W[t*4 + p*1024 .. +3]
    #pragma unroll
    for (int p = 0; p < 4; ++p) {
        int i = t * 4 + p * 1024;
        float4 v = *(const float4*)(W + i);
        int d = i >> 6, k = i & 63;
        Ws[k + 0][d] = v.x;
        Ws[k + 1][d] = v.y;
        Ws[k + 2][d] = v.z;
        Ws[k + 3][d] = v.w;
    }
    if (t < D) bs[t] = b[t];

    int row0 = blockIdx.x * D;
    // stage X tile transposed: 4 passes of 16 rows, float4 per thread
    #pragma unroll
    for (int p = 0; p < 4; ++p) {
        int r = (t >> 4) + p * 16;
        int c = (t & 15) * 4;
        int row = row0 + r;
        float4 v = (row < N) ? *(const float4*)(x + (size_t)row * D + c)
                             : make_float4(0.f, 0.f, 0.f, 0.f);
        Xs[c + 0][r] = v.x;
        Xs[c + 1][r] = v.y;
        Xs[c + 2][r] = v.z;
        Xs[c + 3][r] = v.w;
    }
    __syncthreads();

    int tr = (t >> 4) * 4;    // row offset of this thread's 4x4 tile
    int tc = (t & 15) * 4;    // col offset
    float acc[4][4];
    #pragma unroll
    for (int i = 0; i < 4; ++i)
        #pragma unroll
        for (int j = 0; j < 4; ++j) acc[i][j] = bs[tc + j];

    #pragma unroll 8
    for (int k = 0; k < D; ++k) {
        float4 xv = *(const float4*)(&Xs[k][tr]);
        float4 wv = *(const float4*)(&Ws[k][tc]);
        acc[0][0] += xv.x * wv.x; acc[0][1] += xv.x * wv.y; acc[0][2] += xv.x * wv.z; acc[0][3] += xv.x * wv.w;
        acc[1][0] += xv.y * wv.x; acc[1][1] += xv.y * wv.y; acc[1][2] += xv.y * wv.z; acc[1][3] += xv.y * wv.w;
        acc[2][0] += xv.z * wv.x; acc[2][1] += xv.z * wv.y; acc[2][2] += xv.z * wv.z; acc[2][3] += xv.z * wv.w;
        acc[3][0] += xv.w * wv.x; acc[3][1] += xv.w * wv.y; acc[3][2] += xv.w * wv.z; acc[3][3] += xv.w * wv.w;
    }

    #pragma unroll
    for (int i = 0; i < 4; ++i) {
        int row = row0 + tr + i;
        if (row < N)
            *(float4*)(h + (size_t)row * D + tc) =
                make_float4(acc[i][0], acc[i][1], acc[i][2], acc[i][3]);
    }
}

// K4: CSR fill. Edge e -> slot in its source node's segment; store packed
//     {n2, wd = rd[n2]*exp(-d^2)}.
__global__ __launch_bounds__(256) void fill_kernel(const int* __restrict__ ei,
                                                   const float* __restrict__ dist,
                                                   const float* __restrict__ rd,
                                                   int* __restrict__ cursor,
                                                   uint2* __restrict__ csr, int E) {
    int e = blockIdx.x * 256 + threadIdx.x;
    if (e >= E) return;
    int   n1 = ei[e];
    int   n2 = ei[E + e];
    float dv = dist[e];
    float wd = rd[n2] * __expf(-dv * dv);
    int slot = atomicAdd(&cursor[n1], 1);
    csr[slot] = make_uint2((unsigned)n2, __float_as_uint(wd));
}

// K5: gather-side aggregation + leaky_relu + L2-normalize, fused.
__global__ __launch_bounds__(256) void agg_kernel(const int* __restrict__ row_ptr,
                                                  const float* __restrict__ rd,
                                                  const uint2* __restrict__ csr,
                                                  const float* __restrict__ h,
                                                  float* __restrict__ out, int N) {
    int node = blockIdx.x * 4 + (threadIdx.x >> 6);
    int lane = threadIdx.x & 63;
    if (node >= N) return;
    int s = row_ptr[node];
    int e = row_ptr[node + 1];
    float acc = 0.0f;
    for (int j = s; j < e; ++j) {
        uint2 p  = csr[j];
        float wd = __uint_as_float(p.y);
        acc += wd * h[(size_t)p.x * D + lane];
    }
    acc *= rd[node];
    float v = acc > 0.0f ? acc : 0.01f * acc;
    float ss = v * v;
    #pragma unroll
    for (int m = 32; m; m >>= 1) ss += __shfl_xor(ss, m, 64);
    out[node * D + lane] = v / fmaxf(sqrtf(ss), 1e-12f);
}

extern "C" void kernel_launch(void* const* d_in, const int* in_sizes, int n_in,
                              void* d_out, int out_size, void* d_ws, size_t ws_size,
                              hipStream_t stream) {
    const float* poi  = (const float*)d_in[0];
    const int*   ei   = (const int*)d_in[1];
    const float* dist = (const float*)d_in[2];
    const float* W    = (const float*)d_in[3];
    const float* b    = (const float*)d_in[4];
    float*       out  = (float*)d_out;

    int N = in_sizes[0] / D;   // 100000
    int E = in_sizes[2];       // 1280000

    // Workspace map (extents audited; N=100000 -> N*4 = 0x61A80):
    //   cnt     0x000000 .. 0x061A80
    //   row_ptr 0x080000 .. 0x0E1A84   (N+1 ints)
    //   cursor  0x100000 .. 0x161A80
    //   rd      0x180000 .. 0x1E1A80
    //   bsum    0x1F0000 .. 0x1F0188   (<= 128 ints; MUST NOT overlap rd!)
    //   h       0x200000 .. 0x200000 + N*D*4 (25.6MB)
    //   csr     h_end    .. h_end + E*8 (10.2MB)
    char*  w       = (char*)d_ws;
    int*   cnt     = (int*)(w);
    int*   row_ptr = (int*)(w + 0x80000);
    int*   cursor  = (int*)(w + 0x100000);
    float* rd      = (float*)(w + 0x180000);
    int*   bsum    = (int*)(w + 0x1F0000);
    float* h       = (float*)(w + 0x200000);
    uint2* csr     = (uint2*)(w + 0x200000 + (size_t)N * D * sizeof(float));

    int nb = (N + 1023) / 1024;   // 98 for N=100000 (must be <= 128)

    hipMemsetAsync(cnt, 0, (size_t)N * sizeof(int), stream);

    deg_kernel   <<<(E + 255) / 256, 256, 0, stream>>>(ei, cnt, E);
    scanA_kernel <<<nb, 256, 0, stream>>>(cnt, bsum, N);
    scanB_kernel <<<1, 128, 0, stream>>>(bsum, nb);
    scanC_kernel <<<nb, 256, 0, stream>>>(cnt, bsum, row_ptr, cursor, rd, N, E);
    linear_kernel<<<(N + D - 1) / D, 256, 0, stream>>>(poi, W, b, h, N);
    fill_kernel  <<<(E + 255) / 256, 256, 0, stream>>>(ei, dist, rd, cursor, csr, E);
    agg_kernel   <<<(N + 3) / 4, 256, 0, stream>>>(row_ptr, rd, csr, h, out, N);
}

// Round 6
// 315.108 us; speedup vs baseline: 2.7004x; 1.1322x over previous
//
#include <hip/hip_runtime.h>
#include <hip/hip_bf16.h>

#define D 64

// round-to-nearest-even f32 -> bf16 bits (finite values)
__device__ __forceinline__ unsigned short f2bf(float f) {
    unsigned u = __float_as_uint(f);
    u = (u + 0x7FFF + ((u >> 16) & 1)) >> 16;
    return (unsigned short)u;
}

// ---------------------------------------------------------------------------
// K1: out-degree histogram over source nodes, 4 edges/thread
__global__ __launch_bounds__(256) void deg_kernel(const int* __restrict__ n1,
                                                  int* __restrict__ cnt, int E) {
    int e0 = (blockIdx.x * 256 + threadIdx.x) * 4;
    if (e0 + 3 < E) {
        int4 v = *(const int4*)(n1 + e0);
        atomicAdd(&cnt[v.x], 1);
        atomicAdd(&cnt[v.y], 1);
        atomicAdd(&cnt[v.z], 1);
        atomicAdd(&cnt[v.w], 1);
    } else {
        for (int e = e0; e < E; ++e) atomicAdd(&cnt[n1[e]], 1);
    }
}

// ---------------------------------------------------------------------------
// 3-phase parallel exclusive scan over cnt[N]
__global__ __launch_bounds__(256) void scanA_kernel(const int* __restrict__ cnt,
                                                    int* __restrict__ bsum, int N) {
    int t = threadIdx.x;
    int base = blockIdx.x * 1024 + t * 4;
    int s = 0;
    if (base + 3 < N) {
        int4 v = *(const int4*)(cnt + base);
        s = v.x + v.y + v.z + v.w;
    } else {
        for (int i = base; i < N && i < base + 4; ++i) s += cnt[i];
    }
    #pragma unroll
    for (int m = 32; m; m >>= 1) s += __shfl_xor(s, m, 64);
    __shared__ int ws[4];
    if ((t & 63) == 0) ws[t >> 6] = s;
    __syncthreads();
    if (t == 0) bsum[blockIdx.x] = ws[0] + ws[1] + ws[2] + ws[3];
}

__global__ __launch_bounds__(128) void scanB_kernel(int* __restrict__ bsum, int nb) {
    __shared__ int lds[128];
    int t = threadIdx.x;
    int v = (t < nb) ? bsum[t] : 0;
    lds[t] = v;
    __syncthreads();
    #pragma unroll
    for (int off = 1; off < 128; off <<= 1) {
        int u = (t >= off) ? lds[t - off] : 0;
        __syncthreads();
        lds[t] += u;
        __syncthreads();
    }
    if (t < nb) bsum[t] = lds[t] - v;   // exclusive
}

__global__ __launch_bounds__(256) void scanC_kernel(const int* __restrict__ cnt,
                                                    const int* __restrict__ bsum,
                                                    int* __restrict__ row_ptr,
                                                    int* __restrict__ cursor,
                                                    float* __restrict__ rd,
                                                    int N, int E) {
    int t = threadIdx.x;
    int base = blockIdx.x * 1024 + t * 4;
    int c0 = 0, c1 = 0, c2 = 0, c3 = 0;
    if (base + 3 < N) {
        int4 v = *(const int4*)(cnt + base);
        c0 = v.x; c1 = v.y; c2 = v.z; c3 = v.w;
    } else {
        if (base + 0 < N) c0 = cnt[base + 0];
        if (base + 1 < N) c1 = cnt[base + 1];
        if (base + 2 < N) c2 = cnt[base + 2];
        if (base + 3 < N) c3 = cnt[base + 3];
    }
    int s = c0 + c1 + c2 + c3;
    __shared__ int lds[256];
    lds[t] = s;
    __syncthreads();
    #pragma unroll
    for (int off = 1; off < 256; off <<= 1) {
        int u = (t >= off) ? lds[t - off] : 0;
        __syncthreads();
        lds[t] += u;
        __syncthreads();
    }
    int run = bsum[blockIdx.x] + lds[t] - s;
    int cc[4] = {c0, c1, c2, c3};
    #pragma unroll
    for (int k = 0; k < 4; ++k) {
        int i = base + k;
        if (i < N) {
            row_ptr[i] = run;
            cursor[i]  = run;
            rd[i]      = rsqrtf((float)cc[k]);  // deg >= 1 guaranteed
            run += cc[k];
        }
    }
    if (blockIdx.x == 0 && t == 0) row_ptr[N] = E;
}

// ---------------------------------------------------------------------------
// K3: h2 = bf16( rd[row] * (X @ W^T + b) ).  Register-blocked f32 GEMM,
// 64 rows/block, 4x4 tile/thread.  rd folded here so fill/agg never gather it;
// the rd[n1] factor is dropped entirely (cancels under leaky_relu + normalize).
__global__ __launch_bounds__(256) void linear_kernel(const float* __restrict__ x,
                                                     const float* __restrict__ W,
                                                     const float* __restrict__ b,
                                                     const float* __restrict__ rd,
                                                     unsigned short* __restrict__ h2,
                                                     int N) {
    __shared__ float Ws[D][D + 4];   // Ws[k][d] = W[d*64+k]
    __shared__ float Xs[D][D + 4];   // Xs[k][r] = X[row0+r][k]
    __shared__ float bs[D];
    __shared__ float rds[D];
    int t = threadIdx.x;

    #pragma unroll
    for (int p = 0; p < 4; ++p) {
        int i = t * 4 + p * 1024;
        float4 v = *(const float4*)(W + i);
        int d = i >> 6, k = i & 63;
        Ws[k + 0][d] = v.x;
        Ws[k + 1][d] = v.y;
        Ws[k + 2][d] = v.z;
        Ws[k + 3][d] = v.w;
    }
    int row0 = blockIdx.x * D;
    if (t < D) {
        bs[t] = b[t];
        int row = row0 + t;
        rds[t] = (row < N) ? rd[row] : 0.0f;
    }
    #pragma unroll
    for (int p = 0; p < 4; ++p) {
        int r = (t >> 4) + p * 16;
        int c = (t & 15) * 4;
        int row = row0 + r;
        float4 v = (row < N) ? *(const float4*)(x + (size_t)row * D + c)
                             : make_float4(0.f, 0.f, 0.f, 0.f);
        Xs[c + 0][r] = v.x;
        Xs[c + 1][r] = v.y;
        Xs[c + 2][r] = v.z;
        Xs[c + 3][r] = v.w;
    }
    __syncthreads();

    int tr = (t >> 4) * 4;
    int tc = (t & 15) * 4;
    float acc[4][4];
    #pragma unroll
    for (int i = 0; i < 4; ++i)
        #pragma unroll
        for (int j = 0; j < 4; ++j) acc[i][j] = bs[tc + j];

    #pragma unroll 8
    for (int k = 0; k < D; ++k) {
        float4 xv = *(const float4*)(&Xs[k][tr]);
        float4 wv = *(const float4*)(&Ws[k][tc]);
        acc[0][0] += xv.x * wv.x; acc[0][1] += xv.x * wv.y; acc[0][2] += xv.x * wv.z; acc[0][3] += xv.x * wv.w;
        acc[1][0] += xv.y * wv.x; acc[1][1] += xv.y * wv.y; acc[1][2] += xv.y * wv.z; acc[1][3] += xv.y * wv.w;
        acc[2][0] += xv.z * wv.x; acc[2][1] += xv.z * wv.y; acc[2][2] += xv.z * wv.z; acc[2][3] += xv.z * wv.w;
        acc[3][0] += xv.w * wv.x; acc[3][1] += xv.w * wv.y; acc[3][2] += xv.w * wv.z; acc[3][3] += xv.w * wv.w;
    }

    #pragma unroll
    for (int i = 0; i < 4; ++i) {
        int row = row0 + tr + i;
        if (row < N) {
            float sc = rds[tr + i];
            ushort4 o;
            o.x = f2bf(acc[i][0] * sc);
            o.y = f2bf(acc[i][1] * sc);
            o.z = f2bf(acc[i][2] * sc);
            o.w = f2bf(acc[i][3] * sc);
            *(ushort4*)(h2 + (size_t)row * D + tc) = o;
        }
    }
}

// K4: CSR fill, 4 edges/thread.  wd = exp(-d^2) only — no gathers.
__global__ __launch_bounds__(256) void fill_kernel(const int* __restrict__ ei,
                                                   const float* __restrict__ dist,
                                                   int* __restrict__ cursor,
                                                   uint2* __restrict__ csr, int E) {
    int e0 = (blockIdx.x * 256 + threadIdx.x) * 4;
    const int* n2p = ei + E;
    if (e0 + 3 < E) {
        int4   a = *(const int4*)(ei + e0);
        int4   c = *(const int4*)(n2p + e0);
        float4 d = *(const float4*)(dist + e0);
        int s0 = atomicAdd(&cursor[a.x], 1);
        int s1 = atomicAdd(&cursor[a.y], 1);
        int s2 = atomicAdd(&cursor[a.z], 1);
        int s3 = atomicAdd(&cursor[a.w], 1);
        csr[s0] = make_uint2((unsigned)c.x, __float_as_uint(__expf(-d.x * d.x)));
        csr[s1] = make_uint2((unsigned)c.y, __float_as_uint(__expf(-d.y * d.y)));
        csr[s2] = make_uint2((unsigned)c.z, __float_as_uint(__expf(-d.z * d.z)));
        csr[s3] = make_uint2((unsigned)c.w, __float_as_uint(__expf(-d.w * d.w)));
    } else {
        for (int e = e0; e < E; ++e) {
            float dv = dist[e];
            int slot = atomicAdd(&cursor[ei[e]], 1);
            csr[slot] = make_uint2((unsigned)n2p[e], __float_as_uint(__expf(-dv * dv)));
        }
    }
}

// K5: gather-side aggregation + leaky_relu + L2-normalize.
// One wave per node; bf16 h rows (128B); edge loop unrolled x4 (4 gathers in
// flight, 4 independent accumulators).
__global__ __launch_bounds__(256) void agg_kernel(const int* __restrict__ row_ptr,
                                                  const uint2* __restrict__ csr,
                                                  const unsigned short* __restrict__ h2,
                                                  float* __restrict__ out, int N) {
    int node = blockIdx.x * 4 + (threadIdx.x >> 6);
    int lane = threadIdx.x & 63;
    if (node >= N) return;
    int s = row_ptr[node];
    int e = row_ptr[node + 1];
    float a0 = 0.f, a1 = 0.f, a2 = 0.f, a3 = 0.f;
    int j = s;
    for (; j + 3 < e; j += 4) {
        uint2 p0 = csr[j + 0];
        uint2 p1 = csr[j + 1];
        uint2 p2 = csr[j + 2];
        uint2 p3 = csr[j + 3];
        float v0 = __uint_as_float((unsigned)h2[(size_t)p0.x * D + lane] << 16);
        float v1 = __uint_as_float((unsigned)h2[(size_t)p1.x * D + lane] << 16);
        float v2 = __uint_as_float((unsigned)h2[(size_t)p2.x * D + lane] << 16);
        float v3 = __uint_as_float((unsigned)h2[(size_t)p3.x * D + lane] << 16);
        a0 += __uint_as_float(p0.y) * v0;
        a1 += __uint_as_float(p1.y) * v1;
        a2 += __uint_as_float(p2.y) * v2;
        a3 += __uint_as_float(p3.y) * v3;
    }
    for (; j < e; ++j) {
        uint2 p = csr[j];
        a0 += __uint_as_float(p.y) *
              __uint_as_float((unsigned)h2[(size_t)p.x * D + lane] << 16);
    }
    float acc = (a0 + a1) + (a2 + a3);
    float v = acc > 0.0f ? acc : 0.01f * acc;
    float ss = v * v;
    #pragma unroll
    for (int m = 32; m; m >>= 1) ss += __shfl_xor(ss, m, 64);
    out[node * D + lane] = v / fmaxf(sqrtf(ss), 1e-12f);
}

extern "C" void kernel_launch(void* const* d_in, const int* in_sizes, int n_in,
                              void* d_out, int out_size, void* d_ws, size_t ws_size,
                              hipStream_t stream) {
    const float* poi  = (const float*)d_in[0];
    const int*   ei   = (const int*)d_in[1];
    const float* dist = (const float*)d_in[2];
    const float* W    = (const float*)d_in[3];
    const float* b    = (const float*)d_in[4];
    float*       out  = (float*)d_out;

    int N = in_sizes[0] / D;   // 100000
    int E = in_sizes[2];       // 1280000

    // Workspace map (extents audited; N=100000 -> N*4 = 0x61A80):
    //   cnt     0x000000 .. 0x061A80
    //   row_ptr 0x080000 .. 0x0E1A84   (N+1 ints)
    //   cursor  0x100000 .. 0x161A80
    //   rd      0x180000 .. 0x1E1A80
    //   bsum    0x1F0000 .. 0x1F0188   (128 ints; after rd's end)
    //   h2      0x200000 .. +N*D*2 (12.8MB, bf16)
    //   csr     h2_end   .. +E*8  (10.2MB)
    char*           w       = (char*)d_ws;
    int*            cnt     = (int*)(w);
    int*            row_ptr = (int*)(w + 0x80000);
    int*            cursor  = (int*)(w + 0x100000);
    float*          rd      = (float*)(w + 0x180000);
    int*            bsum    = (int*)(w + 0x1F0000);
    unsigned short* h2      = (unsigned short*)(w + 0x200000);
    uint2*          csr     = (uint2*)(w + 0x200000 + (size_t)N * D * sizeof(unsigned short));

    int nb = (N + 1023) / 1024;   // 98 (must be <= 128)

    hipMemsetAsync(cnt, 0, (size_t)N * sizeof(int), stream);

    deg_kernel   <<<(E / 4 + 255) / 256, 256, 0, stream>>>(ei, cnt, E);
    scanA_kernel <<<nb, 256, 0, stream>>>(cnt, bsum, N);
    scanB_kernel <<<1, 128, 0, stream>>>(bsum, nb);
    scanC_kernel <<<nb, 256, 0, stream>>>(cnt, bsum, row_ptr, cursor, rd, N, E);
    linear_kernel<<<(N + D - 1) / D, 256, 0, stream>>>(poi, W, b, rd, h2, N);
    fill_kernel  <<<(E / 4 + 255) / 256, 256, 0, stream>>>(ei, dist, cursor, csr, E);
    agg_kernel   <<<(N + 3) / 4, 256, 0, stream>>>(row_ptr, csr, h2, out, N);
}